// Round 13
// baseline (104.283 us; speedup 1.0000x reference)
//
#include <hip/hip_runtime.h>

#define UNITS 14336
#define IN_F 4096
#define PACKED 1024
#define CLIP_VAL 100.0f

typedef unsigned int uint32;

using bf16x8 = __attribute__((ext_vector_type(8))) short;   // 8 bf16 = 4 VGPRs
using f32x16 = __attribute__((ext_vector_type(16))) float;  // 32x32 acc

// fp32 -> bf16 round-to-nearest-even
__device__ inline unsigned short f2bf(float f) {
    uint32 u = __float_as_uint(f);
    u += 0x7FFFu + ((u >> 16) & 1u);
    return (unsigned short)(u >> 16);
}

__device__ inline uint32 pack2bf(float a, float b) {
    return (uint32)f2bf(a) | ((uint32)f2bf(b) << 16);
}

// SWAR unpack: one packed byte (0..255, 4 crumbs little-endian) -> two uint32,
// each 2 bf16: r0 = {bf(c0), bf(c1)}, r1 = {bf(c2), bf(c3)}.
// crumb->bf16: 0->0, 1->0x3F80(+1), 2->0xBF80(-1), 3->0x8000(-0.0, MAC-safe)
__device__ inline void unpack_byte(uint32 v, uint32& r0, uint32& r1) {
    uint32 t0 = (v & 3u) | ((v & 0xCu) << 14);
    uint32 t1 = ((v >> 4) & 3u) | ((v & 0xC0u) << 10);
    uint32 s0 = t0 >> 1;
    uint32 s1 = t1 >> 1;
    uint32 nz0 = (t0 ^ s0) & 0x00010001u;
    uint32 nz1 = (t1 ^ s1) & 0x00010001u;
    r0 = nz0 * 0x3F80u + ((s0 & 0x00010001u) << 15);
    r1 = nz1 * 0x3F80u + ((s1 & 0x00010001u) << 15);
}

__device__ inline float clipf(float y) {
    return fminf(fmaxf(y, -CLIP_VAL), CLIP_VAL);
}

// ===== 32x32x16 k-permuted layout =====
// Compacted dword c of pw row n holds original int32 elems 4c..4c+3
// = original k [16c, 16c+16). "Group" G covers k [G*32, G*32+32): dwords
// 2G (lane p=0) and 2G+1 (p=1). Lane p covers k [32G+16p, +16):
//   MFMA step A (k-slots p*8+j): byte0,1 of its dword -> k 32G+16p+j
//   MFMA step B: byte2,3 -> k 32G+16p+8+j
// A-frag (pw): m = lane&31 (unit row), slots (lane>>5)*8+j  [matches ISA]
// B-frag (x):  n = lane&31 (batch),   slots (lane>>5)*8+j
// x granule idx = G*128 + s*64 + lane (16 B = 8 bf16):
//   j -> x[lane&31][G*32 + (lane>>5)*16 + s*8 + j]
// C/D: col = lane&31 = batch, row = (reg&3)+8*(reg>>2)+4*(lane>>5) = unit
//   (first mfma operand = A = pw side -> row; verified convention: col
//    belongs to the SECOND operand, as used in rounds 1-12 epilogues)

// Kernel 1: convert x [32][4096] fp32 -> bf16, 32x32-permuted B-frag order.
__global__ __launch_bounds__(256) void convert_x_kernel(
    const float* __restrict__ x, uint4* __restrict__ ws) {
    int t = blockIdx.x * 256 + threadIdx.x;      // 0..16383 = granule idx
    int lane = t & 63;
    int s = (t >> 6) & 1;
    int G = t >> 7;                              // 0..127
    int n = lane & 31;
    int p = lane >> 5;
    int k0 = G * 32 + p * 16 + s * 8;
    const float4* src = (const float4*)(x + (size_t)n * IN_F + k0);
    float4 lo = src[0];
    float4 hi = src[1];
    uint4 o;
    o.x = pack2bf(lo.x, lo.y);
    o.y = pack2bf(lo.z, lo.w);
    o.z = pack2bf(hi.x, hi.y);
    o.w = pack2bf(hi.z, hi.w);
    ws[t] = o;
}

// Kernel 2: MFMA GEMM v13 — 32-unit tiles via mfma_f32_32x32x16_bf16.
// R12 diagnosis: per-CU ingress was dominated by x-fragments (900 KB/CU vs
// pw's 229 KB) because 16-unit tiles give x only 16-way reuse. 32x32 MFMA
// doubles units/wave -> block count halves (448) -> x device traffic
// 229 -> 114 MB, MFMA+VALU cycles per output halve too.
// Grid: 448 blocks x 512 threads (8 waves). Block tile: 32 units x 32
// batches; wave wid owns G-range [wid*16, +16) (K-split 8), self-stages its
// own pw columns (no barrier before K-loop, R12-style).
// LDS: staging row stride 1028 B (257 dwords == 1 mod 32: frag ds_read_b32
// lands 2 lanes/bank = free); reduce buffer (stride 132) aliases it after a
// barrier. 33.8 KB LDS + 512 threads -> 4 blocks/CU, 32 waves/CU.
__global__ __launch_bounds__(512, 8) void ternary_mm_kernel(
    const uint4* __restrict__ xw,     // permuted bf16 x fragments
    const int*   __restrict__ pw,     // [UNITS][PACKED] packed bytes as int32
    const float* __restrict__ scale,
    const float* __restrict__ bias,
    float*       __restrict__ out) {
    __shared__ uint32 lds4[8448];     // 33792 B: staging (32 x 1028B) / reduce
    char* lds = (char*)lds4;

    const int tid  = threadIdx.x;
    const int wid  = tid >> 6;           // 0..7 = K-split index
    const int lane = tid & 63;
    const int n32  = lane & 31;
    const int p    = lane >> 5;
    const int u0   = blockIdx.x << 5;    // 32 units per block, 448 blocks

    // ---- self-stage: rows 0..31 x compacted dwords [wid*32, +32) ----
    {
        const char* src = (const char*)pw;
        #pragma unroll
        for (int j = 0; j < 16; ++j) {
            const int row = ((j & 7) << 2) + (lane >> 4);          // 0..31
            const int c   = (wid << 5) + ((j >> 3) << 4) + (lane & 15);
            uint4 v = *(const uint4*)(src + (size_t)(u0 + row) * 4096
                                          + ((size_t)c << 4));
            uint32 d = (v.x & 0xFFu) | ((v.y & 0xFFu) << 8)
                     | ((v.z & 0xFFu) << 16) | ((v.w & 0xFFu) << 24);
            *(uint32*)(lds + row * 1028 + (c << 2)) = d;
        }
    }
    // No __syncthreads: each wave reads only the columns it wrote
    // (wave-local lgkmcnt ordering, validated correct in R12).

    f32x16 acc = {0.f,0.f,0.f,0.f,0.f,0.f,0.f,0.f,
                  0.f,0.f,0.f,0.f,0.f,0.f,0.f,0.f};

    // frag base: pw row = n32, dword = 2G+p, G = wid*16 + ig
    const char*  lb = lds + n32 * 1028 + ((((wid << 5)) + p) << 2);
    const uint4* xg = xw + ((wid << 4) << 7) + lane;   // granule G*128 + ...

    #pragma unroll
    for (int ig = 0; ig < 16; ++ig) {
        uint32 w = *(const uint32*)(lb + (ig << 3));   // dword 2G+p (b32, free)
        uint4 x0 = xg[(ig << 7)];                      // s=0 granule
        uint4 x1 = xg[(ig << 7) + 64];                 // s=1 granule

        uint4 fA, fB;                    // step A / step B pw frags
        unpack_byte(w & 0xFFu,         fA.x, fA.y);
        unpack_byte((w >> 8) & 0xFFu,  fA.z, fA.w);
        unpack_byte((w >> 16) & 0xFFu, fB.x, fB.y);
        unpack_byte(w >> 24,           fB.z, fB.w);

        acc = __builtin_amdgcn_mfma_f32_32x32x16_bf16(
            __builtin_bit_cast(bf16x8, fA),
            __builtin_bit_cast(bf16x8, x0), acc, 0, 0, 0);
        acc = __builtin_amdgcn_mfma_f32_32x32x16_bf16(
            __builtin_bit_cast(bf16x8, fB),
            __builtin_bit_cast(bf16x8, x1), acc, 0, 0, 0);
    }

    __syncthreads();                     // all waves done with staging region
    // reduce buffer: float idx = lane*132 + wid*16 + r (132: f4-aligned,
    // bank rotation 4/lane -> ~8-way on 4 b128 stores, negligible)
    {
        float* red = (float*)lds4;
        float4* dst = (float4*)(red + lane * 132 + (wid << 4));
        dst[0] = make_float4(acc[0],  acc[1],  acc[2],  acc[3]);
        dst[1] = make_float4(acc[4],  acc[5],  acc[6],  acc[7]);
        dst[2] = make_float4(acc[8],  acc[9],  acc[10], acc[11]);
        dst[3] = make_float4(acc[12], acc[13], acc[14], acc[15]);
    }
    __syncthreads();

    // Reduce 8 K-partials + epilogue: 512 threads x 2 output elems.
    const float* red = (const float*)lds4;
    #pragma unroll
    for (int e0 = 0; e0 < 2; ++e0) {
        const int e  = (e0 << 9) + tid;      // 0..1023 = acc-lane*16 + reg
        const int lp = e >> 4;               // acc lane 0..63
        const int r  = e & 15;               // acc reg 0..15
        float s = 0.f;
        #pragma unroll
        for (int w = 0; w < 8; ++w)
            s += red[lp * 132 + (w << 4) + r];
        const int m  = (r & 3) + ((r >> 2) << 3) + ((lp >> 5) << 2);  // unit
        const int nb = lp & 31;                                       // batch
        const int u  = u0 + m;
        out[(size_t)nb * UNITS + u] = clipf(s * scale[u] + bias[u]);
    }
}

extern "C" void kernel_launch(void* const* d_in, const int* in_sizes, int n_in,
                              void* d_out, int out_size, void* d_ws, size_t ws_size,
                              hipStream_t stream) {
    const float* x     = (const float*)d_in[0];
    const int*   pw    = (const int*)d_in[1];
    const float* scale = (const float*)d_in[2];
    const float* bias  = (const float*)d_in[3];
    float* out = (float*)d_out;

    // ws usage: 32*4096 bf16 = 256 KB permuted x fragments
    uint4* xw = (uint4*)d_ws;

    convert_x_kernel<<<64, 256, 0, stream>>>(x, xw);
    ternary_mm_kernel<<<UNITS / 32, 512, 0, stream>>>(xw, pw, scale, bias, out);
}